// Round 9
// baseline (960.736 us; speedup 1.0000x reference)
//
#include <hip/hip_runtime.h>

#define N_NODES 100000
#define N_EDGES 600000
#define N_GRAPHS 512

typedef __attribute__((ext_vector_type(8))) short short8;
typedef __attribute__((ext_vector_type(4))) float floatx4;

__device__ __forceinline__ unsigned short f2bf(float f) {   // RNE f32 -> bf16
    unsigned int u = __float_as_uint(f);
    u += 0x7FFFu + ((u >> 16) & 1u);
    return (unsigned short)(u >> 16);
}
__device__ __forceinline__ float bf_lo(unsigned int u) { return __uint_as_float(u << 16); }
__device__ __forceinline__ float bf_hi(unsigned int u) { return __uint_as_float(u & 0xFFFF0000u); }

__device__ __forceinline__ void fma8(float* a, short8 v, float n) {
    union { short8 s; unsigned int u[4]; } c; c.s = v;
    #pragma unroll
    for (int j = 0; j < 4; ++j) {
        a[2 * j]     = fmaf(bf_lo(c.u[j]), n, a[2 * j]);
        a[2 * j + 1] = fmaf(bf_hi(c.u[j]), n, a[2 * j + 1]);
    }
}
__device__ __forceinline__ void init8(float* a, short8 v, float s) {
    union { short8 s; unsigned int u[4]; } c; c.s = v;
    #pragma unroll
    for (int j = 0; j < 4; ++j) {
        a[2 * j]     = bf_lo(c.u[j]) * s;
        a[2 * j + 1] = bf_hi(c.u[j]) * s;
    }
}
__device__ __forceinline__ short8 pack8(const float* a) {
    short8 r;
    #pragma unroll
    for (int j = 0; j < 8; ++j) r[j] = (short)f2bf(a[j]);
    return r;
}

// ---------------------------------------------------------------- degree hist (cnt+binh zeroed by memset)
__global__ void k_hist(const int* __restrict__ dst, int* cnt) {
    int e = blockIdx.x * 256 + threadIdx.x;
    if (e < N_EDGES) atomicAdd(&cnt[dst[e]], 1);
}

// ---------------------------------------------------------------- scan (exclusive over cnt; deg = cnt+1)
// also histograms degree-bin counts for the node permutation
__global__ void k_scan1(const int* __restrict__ cnt, int* __restrict__ part,
                        int* __restrict__ binh) {
    __shared__ int s[256];
    int t = threadIdx.x;
    int i = blockIdx.x * 256 + t;
    int v = (i < N_NODES) ? cnt[i] : 0;
    if (i < N_NODES) atomicAdd(&binh[v < 31 ? v : 31], 1);
    s[t] = v; __syncthreads();
    for (int off = 128; off > 0; off >>= 1) {
        if (t < off) s[t] += s[t + off];
        __syncthreads();
    }
    if (t == 0) part[blockIdx.x] = s[0];
}

// scans part[] AND the 32-entry degree-bin histogram -> bin_cursor bases
__global__ void k_scan2(int* __restrict__ part, int* __restrict__ row_ptr, int nb,
                        const int* __restrict__ binh, int* __restrict__ bin_cursor) {
    __shared__ int s[512];
    int t = threadIdx.x;
    int v = (t < nb) ? part[t] : 0;
    int orig = v;
    s[t] = v; __syncthreads();
    for (int off = 1; off < 512; off <<= 1) {
        int u = (t >= off) ? s[t - off] : 0;
        __syncthreads();
        s[t] += u;
        __syncthreads();
    }
    if (t < nb) part[t] = s[t] - orig;       // exclusive
    if (t == 0) row_ptr[N_NODES] = N_EDGES;
    // ---- 32-bin exclusive scan for perm bases
    __syncthreads();
    if (t < 32) s[t] = binh[t];
    __syncthreads();
    if (t == 0) {
        int acc = 0;
        #pragma unroll
        for (int b = 0; b < 32; ++b) { int c = s[b]; s[b] = acc; acc += c; }
    }
    __syncthreads();
    if (t < 32) bin_cursor[t] = s[t];
}

// scan3: row_ptr/cursor/dis + degree-binned permutation assignment
__global__ void k_scan3(const int* __restrict__ cnt, const int* __restrict__ part,
                        int* __restrict__ row_ptr, int* __restrict__ cursor,
                        float* __restrict__ dis, int* __restrict__ bin_cursor,
                        int* __restrict__ perm) {
    __shared__ int s[256];
    int t = threadIdx.x;
    int i = blockIdx.x * 256 + t;
    int v = (i < N_NODES) ? cnt[i] : 0;
    s[t] = v; __syncthreads();
    for (int off = 1; off < 256; off <<= 1) {
        int u = (t >= off) ? s[t - off] : 0;
        __syncthreads();
        s[t] += u;
        __syncthreads();
    }
    int ex = s[t] - v + part[blockIdx.x];
    if (i < N_NODES) {
        row_ptr[i] = ex; cursor[i] = ex;
        dis[i] = 1.0f / sqrtf((float)(v + 1));   // deg includes self-loop
        int pos = atomicAdd(&bin_cursor[v < 31 ? v : 31], 1);
        perm[pos] = i;                            // nodes grouped by degree bin
    }
}

// ---------------------------------------------------------------- CSR scatter
__global__ void k_scatter(const int* __restrict__ src, const int* __restrict__ dst,
                          const float* __restrict__ dis, int* __restrict__ cursor,
                          int* __restrict__ csr_src, float* __restrict__ csr_norm) {
    int e = blockIdx.x * 256 + threadIdx.x;
    if (e >= N_EDGES) return;
    int s = src[e], d = dst[e];
    int pos = atomicAdd(&cursor[d], 1);
    csr_src[pos] = s;
    csr_norm[pos] = dis[s] * dis[d];
}

// ---------------------------------------------------------------- pack W2/W3 to B-frag order (device fn)
__device__ __forceinline__ void pack_one(const float* __restrict__ W, unsigned short* __restrict__ out,
                                         int idx, int N) {
    int lane = idx & 63;
    int ks = (idx >> 6) & 3;
    int ct = idx >> 8;
    int n = ct * 16 + (lane & 15);
    int kbase = ks * 32 + (lane >> 4) * 8;
    #pragma unroll
    for (int j = 0; j < 8; ++j)
        out[(size_t)idx * 8 + j] = f2bf(W[(size_t)(kbase + j) * N + n]);
}

// ---------------------------------------------------------------- layer 1 fused: agg(F=3) + GEMM 3->128 + b1 + relu -> bf16
// 4 nodes/wave: 16 lanes per node. Last 12 blocks instead pack W2/W3 (fused dispatch).
#define NB1 6250
__global__ __launch_bounds__(256) void k_node1(const float* __restrict__ x,
                                               const float* __restrict__ dis,
                                               const int* __restrict__ row_ptr,
                                               const int* __restrict__ csr_src,
                                               const float* __restrict__ csr_norm,
                                               const float* __restrict__ W1,
                                               const float* __restrict__ b1,
                                               unsigned short* __restrict__ out,
                                               const float* __restrict__ W2,
                                               const float* __restrict__ W3,
                                               unsigned short* __restrict__ Wp2,
                                               unsigned short* __restrict__ Wp3) {
    int tid = threadIdx.x;
    if (blockIdx.x >= NB1) {                         // weight-pack role
        int idx = (blockIdx.x - NB1) * 256 + tid;    // 12 blocks = 3072
        if (idx < 2048) pack_one(W2, Wp2, idx, 128);
        else if (idx < 3072) pack_one(W3, Wp3, idx - 2048, 64);
        return;
    }
    __shared__ float Ws[384];
    __shared__ float bs[128];
    for (int i = tid; i < 384; i += 256) Ws[i] = W1[i];
    if (tid < 128) bs[tid] = b1[tid];
    __syncthreads();
    int gw = (blockIdx.x * 256 + tid) >> 6;          // 25000 waves
    int lane = tid & 63;
    int sub = lane >> 4, l16 = lane & 15;
    int node = gw * 4 + sub;                         // 100000 = 25000*4 exact
    int beg = row_ptr[node], end = row_ptr[node + 1];
    float p0 = 0.f, p1 = 0.f, p2 = 0.f;
    for (int e = beg + l16; e < end; e += 16) {
        int s = csr_src[e];
        float n = csr_norm[e];
        p0 = fmaf(x[s * 3 + 0], n, p0);
        p1 = fmaf(x[s * 3 + 1], n, p1);
        p2 = fmaf(x[s * 3 + 2], n, p2);
    }
    #pragma unroll
    for (int m = 8; m > 0; m >>= 1) {                // butterfly within 16-lane group
        p0 += __shfl_xor(p0, m, 64);
        p1 += __shfl_xor(p1, m, 64);
        p2 += __shfl_xor(p2, m, 64);
    }
    float d = dis[node], s2 = d * d;
    float a0 = fmaf(x[node * 3 + 0], s2, p0);
    float a1 = fmaf(x[node * 3 + 1], s2, p1);
    float a2 = fmaf(x[node * 3 + 2], s2, p2);
    int f = l16 * 8;
    float v[8];
    #pragma unroll
    for (int j = 0; j < 8; ++j)
        v[j] = fmaxf(bs[f + j] + a0 * Ws[f + j] + a1 * Ws[128 + f + j] + a2 * Ws[256 + f + j], 0.f);
    *(short8*)(out + (size_t)node * 128 + f) = pack8(v);
}

// ---------------------------------------------------------------- layers 2+3 fused (degree-binned perm):
// agg(F=128 bf16): 16 lanes/node, 16B short8 gathers -> LDS -> MFMA GEMM2 (+b2, relu) -> LDS -> MFMA GEMM3 -> Q2b
// block = 32 perm-consecutive nodes (same degree bin -> uniform barrier arrival).
__global__ __launch_bounds__(256) void k_layer23(const unsigned short* __restrict__ h1,
                                                 const float* __restrict__ dis,
                                                 const int* __restrict__ row_ptr,
                                                 const int* __restrict__ csr_src,
                                                 const float* __restrict__ csr_norm,
                                                 const int* __restrict__ perm,
                                                 const unsigned short* __restrict__ Wp2,
                                                 const float* __restrict__ b2,
                                                 const unsigned short* __restrict__ Wp3,
                                                 unsigned short* __restrict__ Q2b) {
    __shared__ unsigned short Asb[32][136];   // aggregated h1 tile
    __shared__ unsigned short Hsb[32][136];   // h2 tile
    __shared__ int permS[32];
    int tid = threadIdx.x;
    int wave = tid >> 6, lane = tid & 63;
    int quad = lane >> 4, m16 = lane & 15;
    int base = blockIdx.x * 32;
    if (tid < 32) permS[tid] = perm[base + tid];
    __syncthreads();

    // ---- phase 1: 8 nodes per wave in 2 groups of 4; 16 lanes/node, 8 feats/lane.
    {
        int sub = lane >> 4, l16 = lane & 15;
        int rA = wave * 8 + sub, rB = rA + 4;
        int nodeA = permS[rA], nodeB = permS[rB];
        int begA = row_ptr[nodeA], endA = row_ptr[nodeA + 1];
        int begB = row_ptr[nodeB], endB = row_ptr[nodeB + 1];
        // prefetch idx/norm for both groups (independent -> one latency round)
        int idxA[8], idxB[8]; float nnA[8], nnB[8];
        #pragma unroll
        for (int u = 0; u < 8; ++u) {
            int ee = begA + u; int cl = ee < endA ? ee : endA - 1;
            idxA[u] = csr_src[cl]; nnA[u] = ee < endA ? csr_norm[cl] : 0.0f;
        }
        #pragma unroll
        for (int u = 0; u < 8; ++u) {
            int ee = begB + u; int cl = ee < endB ? ee : endB - 1;
            idxB[u] = csr_src[cl]; nnB[u] = ee < endB ? csr_norm[cl] : 0.0f;
        }
        float dA = dis[nodeA], dB = dis[nodeB];
        short8 selfA = *(const short8*)(h1 + (size_t)nodeA * 128 + l16 * 8);
        short8 selfB = *(const short8*)(h1 + (size_t)nodeB * 128 + l16 * 8);

        // group A: 8 gathers of 16B in flight
        short8 gA[8];
        #pragma unroll
        for (int u = 0; u < 8; ++u)
            gA[u] = *(const short8*)(h1 + (size_t)idxA[u] * 128 + l16 * 8);
        float aA[8];
        init8(aA, selfA, dA * dA);
        #pragma unroll
        for (int u = 0; u < 8; ++u) fma8(aA, gA[u], nnA[u]);
        for (int e = begA + 8; e < endA; e += 8) {       // uniform (binned) remainder
            int idx[8]; float nn[8];
            #pragma unroll
            for (int u = 0; u < 8; ++u) {
                int ee = e + u; int cl = ee < endA ? ee : endA - 1;
                idx[u] = csr_src[cl]; nn[u] = ee < endA ? csr_norm[cl] : 0.0f;
            }
            short8 g[8];
            #pragma unroll
            for (int u = 0; u < 8; ++u)
                g[u] = *(const short8*)(h1 + (size_t)idx[u] * 128 + l16 * 8);
            #pragma unroll
            for (int u = 0; u < 8; ++u) fma8(aA, g[u], nn[u]);
        }
        *(short8*)(&Asb[rA][l16 * 8]) = pack8(aA);

        // group B
        short8 gB[8];
        #pragma unroll
        for (int u = 0; u < 8; ++u)
            gB[u] = *(const short8*)(h1 + (size_t)idxB[u] * 128 + l16 * 8);
        float aB[8];
        init8(aB, selfB, dB * dB);
        #pragma unroll
        for (int u = 0; u < 8; ++u) fma8(aB, gB[u], nnB[u]);
        for (int e = begB + 8; e < endB; e += 8) {
            int idx[8]; float nn[8];
            #pragma unroll
            for (int u = 0; u < 8; ++u) {
                int ee = e + u; int cl = ee < endB ? ee : endB - 1;
                idx[u] = csr_src[cl]; nn[u] = ee < endB ? csr_norm[cl] : 0.0f;
            }
            short8 g[8];
            #pragma unroll
            for (int u = 0; u < 8; ++u)
                g[u] = *(const short8*)(h1 + (size_t)idx[u] * 128 + l16 * 8);
            #pragma unroll
            for (int u = 0; u < 8; ++u) fma8(aB, g[u], nn[u]);
        }
        *(short8*)(&Asb[rB][l16 * 8]) = pack8(aB);
    }
    __syncthreads();

    // ---- phase 2: 32x128 = Asb(32x128) @ Wp2(128x128), +b2, relu -> Hsb
    int mt = wave & 1;                 // row tile (16 rows)
    int ch = wave >> 1;                // column half (64 cols)
    {
        short8 af[4];
        #pragma unroll
        for (int ks = 0; ks < 4; ++ks)
            af[ks] = *(const short8*)(&Asb[mt * 16 + m16][ks * 32 + quad * 8]);
        floatx4 acc[4];
        #pragma unroll
        for (int ct = 0; ct < 4; ++ct) acc[ct] = (floatx4){0.f, 0.f, 0.f, 0.f};
        #pragma unroll
        for (int ct = 0; ct < 4; ++ct) {
            int gct = ch * 4 + ct;
            #pragma unroll
            for (int ks = 0; ks < 4; ++ks) {
                short8 bf = *(const short8*)(Wp2 + ((size_t)(gct * 4 + ks) * 64 + lane) * 8);
                acc[ct] = __builtin_amdgcn_mfma_f32_16x16x32_bf16(af[ks], bf, acc[ct], 0, 0, 0);
            }
        }
        #pragma unroll
        for (int ct = 0; ct < 4; ++ct) {
            int col = (ch * 4 + ct) * 16 + m16;
            float bv = b2[col];
            #pragma unroll
            for (int r = 0; r < 4; ++r) {
                int row = mt * 16 + quad * 4 + r;
                Hsb[row][col] = f2bf(fmaxf(acc[ct][r] + bv, 0.0f));
            }
        }
    }
    __syncthreads();

    // ---- phase 3: 32x64 = Hsb(32x128) @ Wp3(128x64) -> global Q2b rows perm[r] (bf16, no bias)
    {
        int cp = wave >> 1;            // column pair (32 cols)
        short8 hf[4];
        #pragma unroll
        for (int ks = 0; ks < 4; ++ks)
            hf[ks] = *(const short8*)(&Hsb[mt * 16 + m16][ks * 32 + quad * 8]);
        floatx4 acc3[2];
        acc3[0] = (floatx4){0.f, 0.f, 0.f, 0.f};
        acc3[1] = (floatx4){0.f, 0.f, 0.f, 0.f};
        #pragma unroll
        for (int ct = 0; ct < 2; ++ct) {
            int gct = cp * 2 + ct;
            #pragma unroll
            for (int ks = 0; ks < 4; ++ks) {
                short8 bf = *(const short8*)(Wp3 + ((size_t)(gct * 4 + ks) * 64 + lane) * 8);
                acc3[ct] = __builtin_amdgcn_mfma_f32_16x16x32_bf16(hf[ks], bf, acc3[ct], 0, 0, 0);
            }
        }
        #pragma unroll
        for (int ct = 0; ct < 2; ++ct) {
            int col = (cp * 2 + ct) * 16 + m16;
            #pragma unroll
            for (int r = 0; r < 4; ++r) {
                int rloc = mt * 16 + quad * 4 + r;
                long row = permS[rloc];
                Q2b[row * 64 + col] = f2bf(acc3[ct][r]);
            }
        }
    }
}

// ---------------------------------------------------------------- aggregation F=64 bf16 + bias + relu + Wl dot
// 8 perm-consecutive nodes/wave (same degree bin): 8 lanes x 8 feats, single gather round.
__global__ __launch_bounds__(256) void k_agg64_dot(const unsigned short* __restrict__ h,
                                                   const float* __restrict__ dis,
                                                   const int* __restrict__ row_ptr,
                                                   const int* __restrict__ csr_src,
                                                   const float* __restrict__ csr_norm,
                                                   const int* __restrict__ perm,
                                                   const float* __restrict__ bias,
                                                   const float* __restrict__ Wl,
                                                   float* __restrict__ s_out) {
    int gw = (blockIdx.x * 256 + threadIdx.x) >> 6;  // 12500 waves
    int lane = threadIdx.x & 63;
    int sub = lane >> 3, l8 = lane & 7;
    int node = perm[gw * 8 + sub];                   // 100000 = 12500*8 exact
    int beg = row_ptr[node], end = row_ptr[node + 1];
    int idx[8]; float nn[8];
    #pragma unroll
    for (int u = 0; u < 8; ++u) {
        int ee = beg + u; int cl = ee < end ? ee : end - 1;
        idx[u] = csr_src[cl]; nn[u] = ee < end ? csr_norm[cl] : 0.0f;
    }
    float d = dis[node];
    short8 self = *(const short8*)(h + (size_t)node * 64 + l8 * 8);
    short8 g[8];
    #pragma unroll
    for (int u = 0; u < 8; ++u)
        g[u] = *(const short8*)(h + (size_t)idx[u] * 64 + l8 * 8);
    float a[8];
    init8(a, self, d * d);
    #pragma unroll
    for (int u = 0; u < 8; ++u) fma8(a, g[u], nn[u]);
    for (int e = beg + 8; e < end; e += 8) {         // uniform (binned) remainder
        int idx2[8]; float nn2[8];
        #pragma unroll
        for (int u = 0; u < 8; ++u) {
            int ee = e + u; int cl = ee < end ? ee : end - 1;
            idx2[u] = csr_src[cl]; nn2[u] = ee < end ? csr_norm[cl] : 0.0f;
        }
        short8 g2[8];
        #pragma unroll
        for (int u = 0; u < 8; ++u)
            g2[u] = *(const short8*)(h + (size_t)idx2[u] * 64 + l8 * 8);
        #pragma unroll
        for (int u = 0; u < 8; ++u) fma8(a, g2[u], nn2[u]);
    }
    int f = l8 * 8;
    float v = 0.f;
    #pragma unroll
    for (int j = 0; j < 8; ++j)
        v = fmaf(fmaxf(a[j] + bias[f + j], 0.f), Wl[f + j], v);
    #pragma unroll
    for (int m = 4; m > 0; m >>= 1) v += __shfl_xor(v, m, 64);   // reduce within 8-lane group
    if (l8 == 0) s_out[node] = v;
}

// ---------------------------------------------------------------- pool over per-node scalars
__global__ __launch_bounds__(256) void k_pool2(const float* __restrict__ s,
                                               const int* __restrict__ batch,
                                               const float* __restrict__ bl,
                                               float* __restrict__ out) {
    int g = blockIdx.x;
    int tid = threadIdx.x;
    int lo = 0, hi = N_NODES;
    while (lo < hi) { int m = (lo + hi) >> 1; if (batch[m] < g) lo = m + 1; else hi = m; }
    int lo2 = lo, hi2 = N_NODES;
    while (lo2 < hi2) { int m = (lo2 + hi2) >> 1; if (batch[m] < g + 1) lo2 = m + 1; else hi2 = m; }
    float acc = 0.0f;
    for (int n = lo + tid; n < lo2; n += 256) acc += s[n];
    __shared__ float sm[256];
    sm[tid] = acc; __syncthreads();
    for (int off = 128; off > 0; off >>= 1) {
        if (tid < off) sm[tid] += sm[tid + off];
        __syncthreads();
    }
    if (tid == 0) out[g] = sm[0] / fmaxf((float)(lo2 - lo), 1.0f) + bl[0];
}

// ---------------------------------------------------------------- launcher
extern "C" void kernel_launch(void* const* d_in, const int* in_sizes, int n_in,
                              void* d_out, int out_size, void* d_ws, size_t ws_size,
                              hipStream_t stream) {
    const float* x     = (const float*)d_in[0];
    const int*   ei    = (const int*)d_in[1];     // [0..E) = src, [E..2E) = dst
    const int*   batch = (const int*)d_in[2];
    const float* W1 = (const float*)d_in[3];
    const float* b1 = (const float*)d_in[4];
    const float* W2 = (const float*)d_in[5];
    const float* b2 = (const float*)d_in[6];
    const float* W3 = (const float*)d_in[7];
    const float* b3 = (const float*)d_in[8];
    const float* Wl = (const float*)d_in[9];
    const float* bl = (const float*)d_in[10];
    float* out = (float*)d_out;

    const int* e_src = ei;
    const int* e_dst = ei + N_EDGES;

    char* ws = (char*)d_ws;
    size_t off = 0;
    auto alloc = [&](size_t bytes) -> char* {
        char* p = ws + off;
        off = (off + bytes + 255) & ~(size_t)255;
        return p;
    };
    int*   cnt      = (int*)  alloc((size_t)N_NODES * 4);
    int*   binh     = (int*)  alloc(32 * 4);          // contiguous with cnt for one memset
    int*   bin_cur  = (int*)  alloc(32 * 4);
    float* dis      = (float*)alloc((size_t)N_NODES * 4);
    int*   row_ptr  = (int*)  alloc((size_t)(N_NODES + 1) * 4);
    int*   cursor   = (int*)  alloc((size_t)N_NODES * 4);
    int*   part     = (int*)  alloc(1024 * 4);
    int*   perm     = (int*)  alloc((size_t)N_NODES * 4);
    int*   csr_src  = (int*)  alloc((size_t)N_EDGES * 4);
    float* csr_norm = (float*)alloc((size_t)N_EDGES * 4);
    float* nscal    = (float*)alloc((size_t)N_NODES * 4);
    unsigned short* P1b = (unsigned short*)alloc((size_t)N_NODES * 128 * 2); // h1 bf16
    unsigned short* Q2b = (unsigned short*)alloc((size_t)N_NODES * 64 * 2);  // h2@W3 bf16
    unsigned short* Wp2 = (unsigned short*)alloc((size_t)128 * 128 * 2);
    unsigned short* Wp3 = (unsigned short*)alloc((size_t)128 * 64 * 2);

    const int NB_N = (N_NODES + 255) / 256;   // 391
    const int NB_E = (N_EDGES + 255) / 256;

    // zero cnt + binh in one fill (they are adjacent in the carve-up)
    hipMemsetAsync(cnt, 0, (size_t)((char*)binh - (char*)cnt) + 32 * 4, stream);
    k_hist<<<NB_E, 256, 0, stream>>>(e_dst, cnt);
    k_scan1<<<NB_N, 256, 0, stream>>>(cnt, part, binh);
    k_scan2<<<1, 512, 0, stream>>>(part, row_ptr, NB_N, binh, bin_cur);
    k_scan3<<<NB_N, 256, 0, stream>>>(cnt, part, row_ptr, cursor, dis, bin_cur, perm);
    k_scatter<<<NB_E, 256, 0, stream>>>(e_src, e_dst, dis, cursor, csr_src, csr_norm);

    // layer 1 fused: agg(F=3) + GEMM 3->128 + b1 + relu -> bf16 (+12 pack blocks)
    k_node1<<<NB1 + 12, 256, 0, stream>>>(x, dis, row_ptr, csr_src, csr_norm,
                                          W1, b1, P1b, W2, W3, Wp2, Wp3);

    // layers 2+3 fused (perm-binned): agg(F=128) + GEMM2(+b2,relu) + GEMM3 -> Q2b bf16
    k_layer23<<<N_NODES / 32, 256, 0, stream>>>(P1b, dis, row_ptr, csr_src, csr_norm, perm,
                                                Wp2, b2, Wp3, Q2b);

    // layer 3 aggregation + b3 + relu + dot(Wl)  (8 perm-binned nodes/wave)
    k_agg64_dot<<<N_NODES / 8 / 4, 256, 0, stream>>>(Q2b, dis, row_ptr, csr_src, csr_norm, perm,
                                                     b3, Wl, nscal);

    // mean pool (+ bl) over per-node scalars
    k_pool2<<<N_GRAPHS, 256, 0, stream>>>(nscal, batch, bl, out);
}

// Round 10
// 237.808 us; speedup vs baseline: 4.0400x; 4.0400x over previous
//
#include <hip/hip_runtime.h>

#define N_NODES 100000
#define N_EDGES 600000
#define N_GRAPHS 512
#define NB_N 391   // ceil(100000/256)

typedef __attribute__((ext_vector_type(8))) short short8;
typedef __attribute__((ext_vector_type(4))) float floatx4;

__device__ __forceinline__ unsigned short f2bf(float f) {   // RNE f32 -> bf16
    unsigned int u = __float_as_uint(f);
    u += 0x7FFFu + ((u >> 16) & 1u);
    return (unsigned short)(u >> 16);
}
__device__ __forceinline__ float bf_lo(unsigned int u) { return __uint_as_float(u << 16); }
__device__ __forceinline__ float bf_hi(unsigned int u) { return __uint_as_float(u & 0xFFFF0000u); }

__device__ __forceinline__ void fma8(float* a, short8 v, float n) {
    union { short8 s; unsigned int u[4]; } c; c.s = v;
    #pragma unroll
    for (int j = 0; j < 4; ++j) {
        a[2 * j]     = fmaf(bf_lo(c.u[j]), n, a[2 * j]);
        a[2 * j + 1] = fmaf(bf_hi(c.u[j]), n, a[2 * j + 1]);
    }
}
__device__ __forceinline__ void init8(float* a, short8 v, float s) {
    union { short8 s; unsigned int u[4]; } c; c.s = v;
    #pragma unroll
    for (int j = 0; j < 4; ++j) {
        a[2 * j]     = bf_lo(c.u[j]) * s;
        a[2 * j + 1] = bf_hi(c.u[j]) * s;
    }
}
__device__ __forceinline__ short8 pack8(const float* a) {
    short8 r;
    #pragma unroll
    for (int j = 0; j < 8; ++j) r[j] = (short)f2bf(a[j]);
    return r;
}

// ---------------------------------------------------------------- degree hist (cnt zeroed by memset)
__global__ void k_hist(const int* __restrict__ dst, int* cnt) {
    int e = blockIdx.x * 256 + threadIdx.x;
    if (e < N_EDGES) atomicAdd(&cnt[dst[e]], 1);
}

// ---------------------------------------------------------------- scan1: block sums of cnt + per-block bin counts (LDS only)
__global__ void k_scan1(const int* __restrict__ cnt, int* __restrict__ part,
                        int* __restrict__ blockbin) {
    __shared__ int s[256];
    __shared__ int lh[32];
    int t = threadIdx.x;
    if (t < 32) lh[t] = 0;
    __syncthreads();
    int i = blockIdx.x * 256 + t;
    int v = (i < N_NODES) ? cnt[i] : 0;
    if (i < N_NODES) atomicAdd(&lh[v < 31 ? v : 31], 1);   // LDS atomic: banked, cheap
    s[t] = v; __syncthreads();
    for (int off = 128; off > 0; off >>= 1) {
        if (t < off) s[t] += s[t + off];
        __syncthreads();
    }
    if (t == 0) part[blockIdx.x] = s[0];
    if (t < 32) blockbin[t * NB_N + blockIdx.x] = lh[t];   // bin-major layout
}

// ---------------------------------------------------------------- scan2: part[] scan + 12512-entry blockbin scan (in place)
__global__ void k_scan2(int* __restrict__ part, int* __restrict__ row_ptr, int nb,
                        int* __restrict__ blockbin) {
    __shared__ int s[512];
    int t = threadIdx.x;
    int v = (t < nb) ? part[t] : 0;
    int orig = v;
    s[t] = v; __syncthreads();
    for (int off = 1; off < 512; off <<= 1) {
        int u = (t >= off) ? s[t - off] : 0;
        __syncthreads();
        s[t] += u;
        __syncthreads();
    }
    if (t < nb) part[t] = s[t] - orig;       // exclusive
    if (t == 0) row_ptr[N_NODES] = N_EDGES;
    __syncthreads();
    // ---- exclusive scan of blockbin (bin-major, 32*391 entries) -> global perm bases
    const int TOT = 32 * NB_N;               // 12512
    const int CH = (TOT + 511) / 512;        // 25
    int base = t * CH;
    int vals[CH];
    int loc = 0;
    #pragma unroll
    for (int k = 0; k < CH; ++k) {
        int idx = base + k;
        int xv = (idx < TOT) ? blockbin[idx] : 0;
        vals[k] = loc;                        // thread-local exclusive prefix
        loc += xv;
    }
    s[t] = loc; __syncthreads();
    int tot = loc;
    for (int off = 1; off < 512; off <<= 1) {
        int u = (t >= off) ? s[t - off] : 0;
        __syncthreads();
        s[t] += u;
        __syncthreads();
    }
    int tbase = s[t] - tot;                   // exclusive prefix of this thread's chunk
    #pragma unroll
    for (int k = 0; k < CH; ++k) {
        int idx = base + k;
        if (idx < TOT) blockbin[idx] = tbase + vals[k];
    }
}

// ---------------------------------------------------------------- scan3: row_ptr/cursor/dis + binned perm (LDS ranks, no global atomics)
__global__ void k_scan3(const int* __restrict__ cnt, const int* __restrict__ part,
                        int* __restrict__ row_ptr, int* __restrict__ cursor,
                        float* __restrict__ dis, const int* __restrict__ blockbase,
                        int* __restrict__ perm) {
    __shared__ int s[256];
    __shared__ int lh[32];
    __shared__ int lbase[32];
    int t = threadIdx.x;
    if (t < 32) lh[t] = 0;
    __syncthreads();
    int i = blockIdx.x * 256 + t;
    int v = (i < N_NODES) ? cnt[i] : 0;
    int bin = v < 31 ? v : 31;
    int lrank = 0;
    if (i < N_NODES) lrank = atomicAdd(&lh[bin], 1);       // LDS atomic: local rank
    if (t < 32) lbase[t] = blockbase[t * NB_N + blockIdx.x];
    s[t] = v; __syncthreads();
    for (int off = 1; off < 256; off <<= 1) {
        int u = (t >= off) ? s[t - off] : 0;
        __syncthreads();
        s[t] += u;
        __syncthreads();
    }
    int ex = s[t] - v + part[blockIdx.x];
    if (i < N_NODES) {
        row_ptr[i] = ex; cursor[i] = ex;
        dis[i] = 1.0f / sqrtf((float)(v + 1));   // deg includes self-loop
        perm[lbase[bin] + lrank] = i;            // nodes grouped by degree bin
    }
}

// ---------------------------------------------------------------- CSR scatter
__global__ void k_scatter(const int* __restrict__ src, const int* __restrict__ dst,
                          const float* __restrict__ dis, int* __restrict__ cursor,
                          int* __restrict__ csr_src, float* __restrict__ csr_norm) {
    int e = blockIdx.x * 256 + threadIdx.x;
    if (e >= N_EDGES) return;
    int s = src[e], d = dst[e];
    int pos = atomicAdd(&cursor[d], 1);
    csr_src[pos] = s;
    csr_norm[pos] = dis[s] * dis[d];
}

// ---------------------------------------------------------------- pack W2/W3 to B-frag order (device fn)
__device__ __forceinline__ void pack_one(const float* __restrict__ W, unsigned short* __restrict__ out,
                                         int idx, int N) {
    int lane = idx & 63;
    int ks = (idx >> 6) & 3;
    int ct = idx >> 8;
    int n = ct * 16 + (lane & 15);
    int kbase = ks * 32 + (lane >> 4) * 8;
    #pragma unroll
    for (int j = 0; j < 8; ++j)
        out[(size_t)idx * 8 + j] = f2bf(W[(size_t)(kbase + j) * N + n]);
}

// ---------------------------------------------------------------- layer 1 fused: agg(F=3) + GEMM 3->128 + b1 + relu -> bf16
// 4 nodes/wave: 16 lanes per node. Last 12 blocks instead pack W2/W3 (fused dispatch).
#define NB1 6250
__global__ __launch_bounds__(256) void k_node1(const float* __restrict__ x,
                                               const float* __restrict__ dis,
                                               const int* __restrict__ row_ptr,
                                               const int* __restrict__ csr_src,
                                               const float* __restrict__ csr_norm,
                                               const float* __restrict__ W1,
                                               const float* __restrict__ b1,
                                               unsigned short* __restrict__ out,
                                               const float* __restrict__ W2,
                                               const float* __restrict__ W3,
                                               unsigned short* __restrict__ Wp2,
                                               unsigned short* __restrict__ Wp3) {
    int tid = threadIdx.x;
    if (blockIdx.x >= NB1) {                         // weight-pack role
        int idx = (blockIdx.x - NB1) * 256 + tid;    // 12 blocks = 3072
        if (idx < 2048) pack_one(W2, Wp2, idx, 128);
        else if (idx < 3072) pack_one(W3, Wp3, idx - 2048, 64);
        return;
    }
    __shared__ float Ws[384];
    __shared__ float bs[128];
    for (int i = tid; i < 384; i += 256) Ws[i] = W1[i];
    if (tid < 128) bs[tid] = b1[tid];
    __syncthreads();
    int gw = (blockIdx.x * 256 + tid) >> 6;          // 25000 waves
    int lane = tid & 63;
    int sub = lane >> 4, l16 = lane & 15;
    int node = gw * 4 + sub;                         // 100000 = 25000*4 exact
    int beg = row_ptr[node], end = row_ptr[node + 1];
    float p0 = 0.f, p1 = 0.f, p2 = 0.f;
    for (int e = beg + l16; e < end; e += 16) {
        int s = csr_src[e];
        float n = csr_norm[e];
        p0 = fmaf(x[s * 3 + 0], n, p0);
        p1 = fmaf(x[s * 3 + 1], n, p1);
        p2 = fmaf(x[s * 3 + 2], n, p2);
    }
    #pragma unroll
    for (int m = 8; m > 0; m >>= 1) {                // butterfly within 16-lane group
        p0 += __shfl_xor(p0, m, 64);
        p1 += __shfl_xor(p1, m, 64);
        p2 += __shfl_xor(p2, m, 64);
    }
    float d = dis[node], s2 = d * d;
    float a0 = fmaf(x[node * 3 + 0], s2, p0);
    float a1 = fmaf(x[node * 3 + 1], s2, p1);
    float a2 = fmaf(x[node * 3 + 2], s2, p2);
    int f = l16 * 8;
    float v[8];
    #pragma unroll
    for (int j = 0; j < 8; ++j)
        v[j] = fmaxf(bs[f + j] + a0 * Ws[f + j] + a1 * Ws[128 + f + j] + a2 * Ws[256 + f + j], 0.f);
    *(short8*)(out + (size_t)node * 128 + f) = pack8(v);
}

// ---------------------------------------------------------------- layers 2+3 fused (degree-binned perm):
// agg(F=128 bf16): 16 lanes/node, 16B short8 gathers -> LDS -> MFMA GEMM2 (+b2, relu) -> LDS -> MFMA GEMM3 -> Q2b
// block = 32 perm-consecutive nodes (same degree bin -> uniform barrier arrival).
__global__ __launch_bounds__(256) void k_layer23(const unsigned short* __restrict__ h1,
                                                 const float* __restrict__ dis,
                                                 const int* __restrict__ row_ptr,
                                                 const int* __restrict__ csr_src,
                                                 const float* __restrict__ csr_norm,
                                                 const int* __restrict__ perm,
                                                 const unsigned short* __restrict__ Wp2,
                                                 const float* __restrict__ b2,
                                                 const unsigned short* __restrict__ Wp3,
                                                 unsigned short* __restrict__ Q2b) {
    __shared__ unsigned short Asb[32][136];   // aggregated h1 tile
    __shared__ unsigned short Hsb[32][136];   // h2 tile
    __shared__ int permS[32];
    int tid = threadIdx.x;
    int wave = tid >> 6, lane = tid & 63;
    int quad = lane >> 4, m16 = lane & 15;
    int base = blockIdx.x * 32;
    if (tid < 32) permS[tid] = perm[base + tid];
    __syncthreads();

    // ---- phase 1: 8 nodes per wave in 2 groups of 4; 16 lanes/node, 8 feats/lane.
    {
        int sub = lane >> 4, l16 = lane & 15;
        int rA = wave * 8 + sub, rB = rA + 4;
        int nodeA = permS[rA], nodeB = permS[rB];
        int begA = row_ptr[nodeA], endA = row_ptr[nodeA + 1];
        int begB = row_ptr[nodeB], endB = row_ptr[nodeB + 1];
        // prefetch idx/norm for both groups (independent -> one latency round)
        int idxA[8], idxB[8]; float nnA[8], nnB[8];
        #pragma unroll
        for (int u = 0; u < 8; ++u) {
            int ee = begA + u; int cl = ee < endA ? ee : endA - 1;
            idxA[u] = csr_src[cl]; nnA[u] = ee < endA ? csr_norm[cl] : 0.0f;
        }
        #pragma unroll
        for (int u = 0; u < 8; ++u) {
            int ee = begB + u; int cl = ee < endB ? ee : endB - 1;
            idxB[u] = csr_src[cl]; nnB[u] = ee < endB ? csr_norm[cl] : 0.0f;
        }
        float dA = dis[nodeA], dB = dis[nodeB];
        short8 selfA = *(const short8*)(h1 + (size_t)nodeA * 128 + l16 * 8);
        short8 selfB = *(const short8*)(h1 + (size_t)nodeB * 128 + l16 * 8);

        // group A: 8 gathers of 16B in flight
        short8 gA[8];
        #pragma unroll
        for (int u = 0; u < 8; ++u)
            gA[u] = *(const short8*)(h1 + (size_t)idxA[u] * 128 + l16 * 8);
        float aA[8];
        init8(aA, selfA, dA * dA);
        #pragma unroll
        for (int u = 0; u < 8; ++u) fma8(aA, gA[u], nnA[u]);
        for (int e = begA + 8; e < endA; e += 8) {       // uniform (binned) remainder
            int idx[8]; float nn[8];
            #pragma unroll
            for (int u = 0; u < 8; ++u) {
                int ee = e + u; int cl = ee < endA ? ee : endA - 1;
                idx[u] = csr_src[cl]; nn[u] = ee < endA ? csr_norm[cl] : 0.0f;
            }
            short8 g[8];
            #pragma unroll
            for (int u = 0; u < 8; ++u)
                g[u] = *(const short8*)(h1 + (size_t)idx[u] * 128 + l16 * 8);
            #pragma unroll
            for (int u = 0; u < 8; ++u) fma8(aA, g[u], nn[u]);
        }
        *(short8*)(&Asb[rA][l16 * 8]) = pack8(aA);

        // group B
        short8 gB[8];
        #pragma unroll
        for (int u = 0; u < 8; ++u)
            gB[u] = *(const short8*)(h1 + (size_t)idxB[u] * 128 + l16 * 8);
        float aB[8];
        init8(aB, selfB, dB * dB);
        #pragma unroll
        for (int u = 0; u < 8; ++u) fma8(aB, gB[u], nnB[u]);
        for (int e = begB + 8; e < endB; e += 8) {
            int idx[8]; float nn[8];
            #pragma unroll
            for (int u = 0; u < 8; ++u) {
                int ee = e + u; int cl = ee < endB ? ee : endB - 1;
                idx[u] = csr_src[cl]; nn[u] = ee < endB ? csr_norm[cl] : 0.0f;
            }
            short8 g[8];
            #pragma unroll
            for (int u = 0; u < 8; ++u)
                g[u] = *(const short8*)(h1 + (size_t)idx[u] * 128 + l16 * 8);
            #pragma unroll
            for (int u = 0; u < 8; ++u) fma8(aB, g[u], nn[u]);
        }
        *(short8*)(&Asb[rB][l16 * 8]) = pack8(aB);
    }
    __syncthreads();

    // ---- phase 2: 32x128 = Asb(32x128) @ Wp2(128x128), +b2, relu -> Hsb
    int mt = wave & 1;                 // row tile (16 rows)
    int ch = wave >> 1;                // column half (64 cols)
    {
        short8 af[4];
        #pragma unroll
        for (int ks = 0; ks < 4; ++ks)
            af[ks] = *(const short8*)(&Asb[mt * 16 + m16][ks * 32 + quad * 8]);
        floatx4 acc[4];
        #pragma unroll
        for (int ct = 0; ct < 4; ++ct) acc[ct] = (floatx4){0.f, 0.f, 0.f, 0.f};
        #pragma unroll
        for (int ct = 0; ct < 4; ++ct) {
            int gct = ch * 4 + ct;
            #pragma unroll
            for (int ks = 0; ks < 4; ++ks) {
                short8 bf = *(const short8*)(Wp2 + ((size_t)(gct * 4 + ks) * 64 + lane) * 8);
                acc[ct] = __builtin_amdgcn_mfma_f32_16x16x32_bf16(af[ks], bf, acc[ct], 0, 0, 0);
            }
        }
        #pragma unroll
        for (int ct = 0; ct < 4; ++ct) {
            int col = (ch * 4 + ct) * 16 + m16;
            float bv = b2[col];
            #pragma unroll
            for (int r = 0; r < 4; ++r) {
                int row = mt * 16 + quad * 4 + r;
                Hsb[row][col] = f2bf(fmaxf(acc[ct][r] + bv, 0.0f));
            }
        }
    }
    __syncthreads();

    // ---- phase 3: 32x64 = Hsb(32x128) @ Wp3(128x64) -> global Q2b rows perm[r] (bf16, no bias)
    {
        int cp = wave >> 1;            // column pair (32 cols)
        short8 hf[4];
        #pragma unroll
        for (int ks = 0; ks < 4; ++ks)
            hf[ks] = *(const short8*)(&Hsb[mt * 16 + m16][ks * 32 + quad * 8]);
        floatx4 acc3[2];
        acc3[0] = (floatx4){0.f, 0.f, 0.f, 0.f};
        acc3[1] = (floatx4){0.f, 0.f, 0.f, 0.f};
        #pragma unroll
        for (int ct = 0; ct < 2; ++ct) {
            int gct = cp * 2 + ct;
            #pragma unroll
            for (int ks = 0; ks < 4; ++ks) {
                short8 bf = *(const short8*)(Wp3 + ((size_t)(gct * 4 + ks) * 64 + lane) * 8);
                acc3[ct] = __builtin_amdgcn_mfma_f32_16x16x32_bf16(hf[ks], bf, acc3[ct], 0, 0, 0);
            }
        }
        #pragma unroll
        for (int ct = 0; ct < 2; ++ct) {
            int col = (cp * 2 + ct) * 16 + m16;
            #pragma unroll
            for (int r = 0; r < 4; ++r) {
                int rloc = mt * 16 + quad * 4 + r;
                long row = permS[rloc];
                Q2b[row * 64 + col] = f2bf(acc3[ct][r]);
            }
        }
    }
}

// ---------------------------------------------------------------- aggregation F=64 bf16 + bias + relu + Wl dot
// 8 perm-consecutive nodes/wave (same degree bin): 8 lanes x 8 feats, single gather round.
__global__ __launch_bounds__(256) void k_agg64_dot(const unsigned short* __restrict__ h,
                                                   const float* __restrict__ dis,
                                                   const int* __restrict__ row_ptr,
                                                   const int* __restrict__ csr_src,
                                                   const float* __restrict__ csr_norm,
                                                   const int* __restrict__ perm,
                                                   const float* __restrict__ bias,
                                                   const float* __restrict__ Wl,
                                                   float* __restrict__ s_out) {
    int gw = (blockIdx.x * 256 + threadIdx.x) >> 6;  // 12500 waves
    int lane = threadIdx.x & 63;
    int sub = lane >> 3, l8 = lane & 7;
    int node = perm[gw * 8 + sub];                   // 100000 = 12500*8 exact
    int beg = row_ptr[node], end = row_ptr[node + 1];
    int idx[8]; float nn[8];
    #pragma unroll
    for (int u = 0; u < 8; ++u) {
        int ee = beg + u; int cl = ee < end ? ee : end - 1;
        idx[u] = csr_src[cl]; nn[u] = ee < end ? csr_norm[cl] : 0.0f;
    }
    float d = dis[node];
    short8 self = *(const short8*)(h + (size_t)node * 64 + l8 * 8);
    short8 g[8];
    #pragma unroll
    for (int u = 0; u < 8; ++u)
        g[u] = *(const short8*)(h + (size_t)idx[u] * 64 + l8 * 8);
    float a[8];
    init8(a, self, d * d);
    #pragma unroll
    for (int u = 0; u < 8; ++u) fma8(a, g[u], nn[u]);
    for (int e = beg + 8; e < end; e += 8) {         // uniform (binned) remainder
        int idx2[8]; float nn2[8];
        #pragma unroll
        for (int u = 0; u < 8; ++u) {
            int ee = e + u; int cl = ee < end ? ee : end - 1;
            idx2[u] = csr_src[cl]; nn2[u] = ee < end ? csr_norm[cl] : 0.0f;
        }
        short8 g2[8];
        #pragma unroll
        for (int u = 0; u < 8; ++u)
            g2[u] = *(const short8*)(h + (size_t)idx2[u] * 64 + l8 * 8);
        #pragma unroll
        for (int u = 0; u < 8; ++u) fma8(a, g2[u], nn2[u]);
    }
    int f = l8 * 8;
    float v = 0.f;
    #pragma unroll
    for (int j = 0; j < 8; ++j)
        v = fmaf(fmaxf(a[j] + bias[f + j], 0.f), Wl[f + j], v);
    #pragma unroll
    for (int m = 4; m > 0; m >>= 1) v += __shfl_xor(v, m, 64);   // reduce within 8-lane group
    if (l8 == 0) s_out[node] = v;
}

// ---------------------------------------------------------------- pool over per-node scalars
__global__ __launch_bounds__(256) void k_pool2(const float* __restrict__ s,
                                               const int* __restrict__ batch,
                                               const float* __restrict__ bl,
                                               float* __restrict__ out) {
    int g = blockIdx.x;
    int tid = threadIdx.x;
    int lo = 0, hi = N_NODES;
    while (lo < hi) { int m = (lo + hi) >> 1; if (batch[m] < g) lo = m + 1; else hi = m; }
    int lo2 = lo, hi2 = N_NODES;
    while (lo2 < hi2) { int m = (lo2 + hi2) >> 1; if (batch[m] < g + 1) lo2 = m + 1; else hi2 = m; }
    float acc = 0.0f;
    for (int n = lo + tid; n < lo2; n += 256) acc += s[n];
    __shared__ float sm[256];
    sm[tid] = acc; __syncthreads();
    for (int off = 128; off > 0; off >>= 1) {
        if (tid < off) sm[tid] += sm[tid + off];
        __syncthreads();
    }
    if (tid == 0) out[g] = sm[0] / fmaxf((float)(lo2 - lo), 1.0f) + bl[0];
}

// ---------------------------------------------------------------- launcher
extern "C" void kernel_launch(void* const* d_in, const int* in_sizes, int n_in,
                              void* d_out, int out_size, void* d_ws, size_t ws_size,
                              hipStream_t stream) {
    const float* x     = (const float*)d_in[0];
    const int*   ei    = (const int*)d_in[1];     // [0..E) = src, [E..2E) = dst
    const int*   batch = (const int*)d_in[2];
    const float* W1 = (const float*)d_in[3];
    const float* b1 = (const float*)d_in[4];
    const float* W2 = (const float*)d_in[5];
    const float* b2 = (const float*)d_in[6];
    const float* W3 = (const float*)d_in[7];
    const float* b3 = (const float*)d_in[8];
    const float* Wl = (const float*)d_in[9];
    const float* bl = (const float*)d_in[10];
    float* out = (float*)d_out;

    const int* e_src = ei;
    const int* e_dst = ei + N_EDGES;

    char* ws = (char*)d_ws;
    size_t off = 0;
    auto alloc = [&](size_t bytes) -> char* {
        char* p = ws + off;
        off = (off + bytes + 255) & ~(size_t)255;
        return p;
    };
    int*   cnt      = (int*)  alloc((size_t)N_NODES * 4);
    int*   blockbin = (int*)  alloc((size_t)32 * NB_N * 4);   // per-block bin counts -> bases
    float* dis      = (float*)alloc((size_t)N_NODES * 4);
    int*   row_ptr  = (int*)  alloc((size_t)(N_NODES + 1) * 4);
    int*   cursor   = (int*)  alloc((size_t)N_NODES * 4);
    int*   part     = (int*)  alloc(1024 * 4);
    int*   perm     = (int*)  alloc((size_t)N_NODES * 4);
    int*   csr_src  = (int*)  alloc((size_t)N_EDGES * 4);
    float* csr_norm = (float*)alloc((size_t)N_EDGES * 4);
    float* nscal    = (float*)alloc((size_t)N_NODES * 4);
    unsigned short* P1b = (unsigned short*)alloc((size_t)N_NODES * 128 * 2); // h1 bf16
    unsigned short* Q2b = (unsigned short*)alloc((size_t)N_NODES * 64 * 2);  // h2@W3 bf16
    unsigned short* Wp2 = (unsigned short*)alloc((size_t)128 * 128 * 2);
    unsigned short* Wp3 = (unsigned short*)alloc((size_t)128 * 64 * 2);

    const int NB_E = (N_EDGES + 255) / 256;

    hipMemsetAsync(cnt, 0, (size_t)N_NODES * 4, stream);
    k_hist<<<NB_E, 256, 0, stream>>>(e_dst, cnt);
    k_scan1<<<NB_N, 256, 0, stream>>>(cnt, part, blockbin);
    k_scan2<<<1, 512, 0, stream>>>(part, row_ptr, NB_N, blockbin);
    k_scan3<<<NB_N, 256, 0, stream>>>(cnt, part, row_ptr, cursor, dis, blockbin, perm);
    k_scatter<<<NB_E, 256, 0, stream>>>(e_src, e_dst, dis, cursor, csr_src, csr_norm);

    // layer 1 fused: agg(F=3) + GEMM 3->128 + b1 + relu -> bf16 (+12 pack blocks)
    k_node1<<<NB1 + 12, 256, 0, stream>>>(x, dis, row_ptr, csr_src, csr_norm,
                                          W1, b1, P1b, W2, W3, Wp2, Wp3);

    // layers 2+3 fused (perm-binned): agg(F=128) + GEMM2(+b2,relu) + GEMM3 -> Q2b bf16
    k_layer23<<<N_NODES / 32, 256, 0, stream>>>(P1b, dis, row_ptr, csr_src, csr_norm, perm,
                                                Wp2, b2, Wp3, Q2b);

    // layer 3 aggregation + b3 + relu + dot(Wl)  (8 perm-binned nodes/wave)
    k_agg64_dot<<<N_NODES / 8 / 4, 256, 0, stream>>>(Q2b, dis, row_ptr, csr_src, csr_norm, perm,
                                                     b3, Wl, nscal);

    // mean pool (+ bl) over per-node scalars
    k_pool2<<<N_GRAPHS, 256, 0, stream>>>(nscal, batch, bl, out);
}

// Round 11
// 221.610 us; speedup vs baseline: 4.3353x; 1.0731x over previous
//
#include <hip/hip_runtime.h>

#define N_NODES 100000
#define N_EDGES 600000
#define N_GRAPHS 512

typedef __attribute__((ext_vector_type(8))) short short8;
typedef __attribute__((ext_vector_type(4))) float floatx4;

__device__ __forceinline__ unsigned short f2bf(float f) {   // RNE f32 -> bf16
    unsigned int u = __float_as_uint(f);
    u += 0x7FFFu + ((u >> 16) & 1u);
    return (unsigned short)(u >> 16);
}
__device__ __forceinline__ float bf_lo(unsigned int u) { return __uint_as_float(u << 16); }
__device__ __forceinline__ float bf_hi(unsigned int u) { return __uint_as_float(u & 0xFFFF0000u); }

__device__ __forceinline__ void fma8(float* a, short8 v, float n) {
    union { short8 s; unsigned int u[4]; } c; c.s = v;
    #pragma unroll
    for (int j = 0; j < 4; ++j) {
        a[2 * j]     = fmaf(bf_lo(c.u[j]), n, a[2 * j]);
        a[2 * j + 1] = fmaf(bf_hi(c.u[j]), n, a[2 * j + 1]);
    }
}
__device__ __forceinline__ void init8(float* a, short8 v, float s) {
    union { short8 s; unsigned int u[4]; } c; c.s = v;
    #pragma unroll
    for (int j = 0; j < 4; ++j) {
        a[2 * j]     = bf_lo(c.u[j]) * s;
        a[2 * j + 1] = bf_hi(c.u[j]) * s;
    }
}
__device__ __forceinline__ short8 pack8(const float* a) {
    short8 r;
    #pragma unroll
    for (int j = 0; j < 8; ++j) r[j] = (short)f2bf(a[j]);
    return r;
}

// ---------------------------------------------------------------- degree hist (cnt zeroed by memset)
__global__ void k_hist(const int* __restrict__ dst, int* cnt) {
    int e = blockIdx.x * 256 + threadIdx.x;
    if (e < N_EDGES) atomicAdd(&cnt[dst[e]], 1);
}

// ---------------------------------------------------------------- scan1: block sums of cnt
__global__ void k_scan1(const int* __restrict__ cnt, int* __restrict__ part) {
    __shared__ int s[256];
    int t = threadIdx.x;
    int i = blockIdx.x * 256 + t;
    int v = (i < N_NODES) ? cnt[i] : 0;
    s[t] = v; __syncthreads();
    for (int off = 128; off > 0; off >>= 1) {
        if (t < off) s[t] += s[t + off];
        __syncthreads();
    }
    if (t == 0) part[blockIdx.x] = s[0];
}

// ---------------------------------------------------------------- scan3: computes its own base from part[]
// (k_scan2 eliminated: 391-int strided reduction per block, all L2 hits)
__global__ void k_scan3(const int* __restrict__ cnt, const int* __restrict__ part,
                        int* __restrict__ row_ptr, int* __restrict__ cursor,
                        float* __restrict__ dis) {
    __shared__ int s[256];
    __shared__ int pbaseS;
    int t = threadIdx.x;
    int psum = 0;
    for (int k = t; k < blockIdx.x; k += 256) psum += part[k];
    s[t] = psum; __syncthreads();
    for (int off = 128; off > 0; off >>= 1) {
        if (t < off) s[t] += s[t + off];
        __syncthreads();
    }
    if (t == 0) pbaseS = s[0];
    __syncthreads();
    int pbase = pbaseS;
    __syncthreads();
    int i = blockIdx.x * 256 + t;
    int v = (i < N_NODES) ? cnt[i] : 0;
    s[t] = v; __syncthreads();
    for (int off = 1; off < 256; off <<= 1) {
        int u = (t >= off) ? s[t - off] : 0;
        __syncthreads();
        s[t] += u;
        __syncthreads();
    }
    int ex = s[t] - v + pbase;
    if (i < N_NODES) {
        row_ptr[i] = ex; cursor[i] = ex;
        dis[i] = 1.0f / sqrtf((float)(v + 1));   // deg includes self-loop
    }
    if (blockIdx.x == 0 && t == 0) row_ptr[N_NODES] = N_EDGES;
}

// ---------------------------------------------------------------- CSR scatter
__global__ void k_scatter(const int* __restrict__ src, const int* __restrict__ dst,
                          const float* __restrict__ dis, int* __restrict__ cursor,
                          int* __restrict__ csr_src, float* __restrict__ csr_norm) {
    int e = blockIdx.x * 256 + threadIdx.x;
    if (e >= N_EDGES) return;
    int s = src[e], d = dst[e];
    int pos = atomicAdd(&cursor[d], 1);
    csr_src[pos] = s;
    csr_norm[pos] = dis[s] * dis[d];
}

// ---------------------------------------------------------------- pack W2/W3 to B-frag order (device fn)
__device__ __forceinline__ void pack_one(const float* __restrict__ W, unsigned short* __restrict__ out,
                                         int idx, int N) {
    int lane = idx & 63;
    int ks = (idx >> 6) & 3;
    int ct = idx >> 8;
    int n = ct * 16 + (lane & 15);
    int kbase = ks * 32 + (lane >> 4) * 8;
    #pragma unroll
    for (int j = 0; j < 8; ++j)
        out[(size_t)idx * 8 + j] = f2bf(W[(size_t)(kbase + j) * N + n]);
}

// ---------------------------------------------------------------- layer 1 fused: agg(F=3) + GEMM 3->128 + b1 + relu -> bf16
// 4 nodes/wave: 16 lanes per node. Last 12 blocks instead pack W2/W3 (fused dispatch).
#define NB1 6250
__global__ __launch_bounds__(256) void k_node1(const float* __restrict__ x,
                                               const float* __restrict__ dis,
                                               const int* __restrict__ row_ptr,
                                               const int* __restrict__ csr_src,
                                               const float* __restrict__ csr_norm,
                                               const float* __restrict__ W1,
                                               const float* __restrict__ b1,
                                               unsigned short* __restrict__ out,
                                               const float* __restrict__ W2,
                                               const float* __restrict__ W3,
                                               unsigned short* __restrict__ Wp2,
                                               unsigned short* __restrict__ Wp3) {
    int tid = threadIdx.x;
    if (blockIdx.x >= NB1) {                         // weight-pack role
        int idx = (blockIdx.x - NB1) * 256 + tid;    // 12 blocks = 3072
        if (idx < 2048) pack_one(W2, Wp2, idx, 128);
        else if (idx < 3072) pack_one(W3, Wp3, idx - 2048, 64);
        return;
    }
    __shared__ float Ws[384];
    __shared__ float bs[128];
    for (int i = tid; i < 384; i += 256) Ws[i] = W1[i];
    if (tid < 128) bs[tid] = b1[tid];
    __syncthreads();
    int gw = (blockIdx.x * 256 + tid) >> 6;          // 25000 waves
    int lane = tid & 63;
    int sub = lane >> 4, l16 = lane & 15;
    int node = gw * 4 + sub;                         // 100000 = 25000*4 exact
    int beg = row_ptr[node], end = row_ptr[node + 1];
    float p0 = 0.f, p1 = 0.f, p2 = 0.f;
    for (int e = beg + l16; e < end; e += 16) {
        int s = csr_src[e];
        float n = csr_norm[e];
        p0 = fmaf(x[s * 3 + 0], n, p0);
        p1 = fmaf(x[s * 3 + 1], n, p1);
        p2 = fmaf(x[s * 3 + 2], n, p2);
    }
    #pragma unroll
    for (int m = 8; m > 0; m >>= 1) {                // butterfly within 16-lane group
        p0 += __shfl_xor(p0, m, 64);
        p1 += __shfl_xor(p1, m, 64);
        p2 += __shfl_xor(p2, m, 64);
    }
    float d = dis[node], s2 = d * d;
    float a0 = fmaf(x[node * 3 + 0], s2, p0);
    float a1 = fmaf(x[node * 3 + 1], s2, p1);
    float a2 = fmaf(x[node * 3 + 2], s2, p2);
    int f = l16 * 8;
    float v[8];
    #pragma unroll
    for (int j = 0; j < 8; ++j)
        v[j] = fmaxf(bs[f + j] + a0 * Ws[f + j] + a1 * Ws[128 + f + j] + a2 * Ws[256 + f + j], 0.f);
    *(short8*)(out + (size_t)node * 128 + f) = pack8(v);
}

// ---------------------------------------------------------------- layers 2+3 fused (natural node order):
// agg(F=128 bf16): 16 lanes/node, 16B short8 gathers, idx for both node-groups prefetched.
// -> LDS -> MFMA GEMM2 (+b2, relu) -> LDS -> MFMA GEMM3 -> Q2b
// block = 32 consecutive nodes (100000 = 3125 * 32 exact). LDS rows padded to 136 ushorts.
__global__ __launch_bounds__(256) void k_layer23(const unsigned short* __restrict__ h1,
                                                 const float* __restrict__ dis,
                                                 const int* __restrict__ row_ptr,
                                                 const int* __restrict__ csr_src,
                                                 const float* __restrict__ csr_norm,
                                                 const unsigned short* __restrict__ Wp2,
                                                 const float* __restrict__ b2,
                                                 const unsigned short* __restrict__ Wp3,
                                                 unsigned short* __restrict__ Q2b) {
    __shared__ unsigned short Asb[32][136];   // aggregated h1 tile
    __shared__ unsigned short Hsb[32][136];   // h2 tile
    int tid = threadIdx.x;
    int wave = tid >> 6, lane = tid & 63;
    int quad = lane >> 4, m16 = lane & 15;
    int base = blockIdx.x * 32;

    // ---- phase 1: 8 nodes per wave in 2 groups of 4; 16 lanes/node, 8 feats/lane.
    {
        int sub = lane >> 4, l16 = lane & 15;
        int rA = wave * 8 + sub, rB = rA + 4;
        int nodeA = base + rA, nodeB = base + rB;
        int begA = row_ptr[nodeA], endA = row_ptr[nodeA + 1];
        int begB = row_ptr[nodeB], endB = row_ptr[nodeB + 1];
        // prefetch idx/norm for both groups (independent -> one latency round)
        int idxA[8], idxB[8]; float nnA[8], nnB[8];
        #pragma unroll
        for (int u = 0; u < 8; ++u) {
            int ee = begA + u; int cl = ee < endA ? ee : endA - 1;
            idxA[u] = csr_src[cl]; nnA[u] = ee < endA ? csr_norm[cl] : 0.0f;
        }
        #pragma unroll
        for (int u = 0; u < 8; ++u) {
            int ee = begB + u; int cl = ee < endB ? ee : endB - 1;
            idxB[u] = csr_src[cl]; nnB[u] = ee < endB ? csr_norm[cl] : 0.0f;
        }
        float dA = dis[nodeA], dB = dis[nodeB];
        short8 selfA = *(const short8*)(h1 + (size_t)nodeA * 128 + l16 * 8);
        short8 selfB = *(const short8*)(h1 + (size_t)nodeB * 128 + l16 * 8);

        // group A: 8 gathers of 16B in flight
        short8 gA[8];
        #pragma unroll
        for (int u = 0; u < 8; ++u)
            gA[u] = *(const short8*)(h1 + (size_t)idxA[u] * 128 + l16 * 8);
        float aA[8];
        init8(aA, selfA, dA * dA);
        #pragma unroll
        for (int u = 0; u < 8; ++u) fma8(aA, gA[u], nnA[u]);
        for (int e = begA + 8; e < endA; e += 8) {       // rare remainder
            int idx[8]; float nn[8];
            #pragma unroll
            for (int u = 0; u < 8; ++u) {
                int ee = e + u; int cl = ee < endA ? ee : endA - 1;
                idx[u] = csr_src[cl]; nn[u] = ee < endA ? csr_norm[cl] : 0.0f;
            }
            short8 g[8];
            #pragma unroll
            for (int u = 0; u < 8; ++u)
                g[u] = *(const short8*)(h1 + (size_t)idx[u] * 128 + l16 * 8);
            #pragma unroll
            for (int u = 0; u < 8; ++u) fma8(aA, g[u], nn[u]);
        }
        *(short8*)(&Asb[rA][l16 * 8]) = pack8(aA);

        // group B
        short8 gB[8];
        #pragma unroll
        for (int u = 0; u < 8; ++u)
            gB[u] = *(const short8*)(h1 + (size_t)idxB[u] * 128 + l16 * 8);
        float aB[8];
        init8(aB, selfB, dB * dB);
        #pragma unroll
        for (int u = 0; u < 8; ++u) fma8(aB, gB[u], nnB[u]);
        for (int e = begB + 8; e < endB; e += 8) {
            int idx[8]; float nn[8];
            #pragma unroll
            for (int u = 0; u < 8; ++u) {
                int ee = e + u; int cl = ee < endB ? ee : endB - 1;
                idx[u] = csr_src[cl]; nn[u] = ee < endB ? csr_norm[cl] : 0.0f;
            }
            short8 g[8];
            #pragma unroll
            for (int u = 0; u < 8; ++u)
                g[u] = *(const short8*)(h1 + (size_t)idx[u] * 128 + l16 * 8);
            #pragma unroll
            for (int u = 0; u < 8; ++u) fma8(aB, g[u], nn[u]);
        }
        *(short8*)(&Asb[rB][l16 * 8]) = pack8(aB);
    }
    __syncthreads();

    // ---- phase 2: 32x128 = Asb(32x128) @ Wp2(128x128), +b2, relu -> Hsb
    int mt = wave & 1;                 // row tile (16 rows)
    int ch = wave >> 1;                // column half (64 cols)
    {
        short8 af[4];
        #pragma unroll
        for (int ks = 0; ks < 4; ++ks)
            af[ks] = *(const short8*)(&Asb[mt * 16 + m16][ks * 32 + quad * 8]);
        floatx4 acc[4];
        #pragma unroll
        for (int ct = 0; ct < 4; ++ct) acc[ct] = (floatx4){0.f, 0.f, 0.f, 0.f};
        #pragma unroll
        for (int ct = 0; ct < 4; ++ct) {
            int gct = ch * 4 + ct;
            #pragma unroll
            for (int ks = 0; ks < 4; ++ks) {
                short8 bf = *(const short8*)(Wp2 + ((size_t)(gct * 4 + ks) * 64 + lane) * 8);
                acc[ct] = __builtin_amdgcn_mfma_f32_16x16x32_bf16(af[ks], bf, acc[ct], 0, 0, 0);
            }
        }
        #pragma unroll
        for (int ct = 0; ct < 4; ++ct) {
            int col = (ch * 4 + ct) * 16 + m16;
            float bv = b2[col];
            #pragma unroll
            for (int r = 0; r < 4; ++r) {
                int row = mt * 16 + quad * 4 + r;
                Hsb[row][col] = f2bf(fmaxf(acc[ct][r] + bv, 0.0f));
            }
        }
    }
    __syncthreads();

    // ---- phase 3: 32x64 = Hsb(32x128) @ Wp3(128x64) -> global Q2b (bf16, no bias)
    {
        int cp = wave >> 1;            // column pair (32 cols)
        short8 hf[4];
        #pragma unroll
        for (int ks = 0; ks < 4; ++ks)
            hf[ks] = *(const short8*)(&Hsb[mt * 16 + m16][ks * 32 + quad * 8]);
        floatx4 acc3[2];
        acc3[0] = (floatx4){0.f, 0.f, 0.f, 0.f};
        acc3[1] = (floatx4){0.f, 0.f, 0.f, 0.f};
        #pragma unroll
        for (int ct = 0; ct < 2; ++ct) {
            int gct = cp * 2 + ct;
            #pragma unroll
            for (int ks = 0; ks < 4; ++ks) {
                short8 bf = *(const short8*)(Wp3 + ((size_t)(gct * 4 + ks) * 64 + lane) * 8);
                acc3[ct] = __builtin_amdgcn_mfma_f32_16x16x32_bf16(hf[ks], bf, acc3[ct], 0, 0, 0);
            }
        }
        #pragma unroll
        for (int ct = 0; ct < 2; ++ct) {
            int col = (cp * 2 + ct) * 16 + m16;
            #pragma unroll
            for (int r = 0; r < 4; ++r) {
                long row = base + mt * 16 + quad * 4 + r;
                Q2b[row * 64 + col] = f2bf(acc3[ct][r]);
            }
        }
    }
}

// ---------------------------------------------------------------- aggregation F=64 bf16 + bias + relu + Wl dot
// 8 nodes/wave: 8 lanes x 8 feats (16B short8 gathers), single gather round.
__global__ __launch_bounds__(256) void k_agg64_dot(const unsigned short* __restrict__ h,
                                                   const float* __restrict__ dis,
                                                   const int* __restrict__ row_ptr,
                                                   const int* __restrict__ csr_src,
                                                   const float* __restrict__ csr_norm,
                                                   const float* __restrict__ bias,
                                                   const float* __restrict__ Wl,
                                                   float* __restrict__ s_out) {
    int gw = (blockIdx.x * 256 + threadIdx.x) >> 6;  // 12500 waves
    int lane = threadIdx.x & 63;
    int sub = lane >> 3, l8 = lane & 7;
    int node = gw * 8 + sub;                         // 100000 = 12500*8 exact
    int beg = row_ptr[node], end = row_ptr[node + 1];
    int idx[8]; float nn[8];
    #pragma unroll
    for (int u = 0; u < 8; ++u) {
        int ee = beg + u; int cl = ee < end ? ee : end - 1;
        idx[u] = csr_src[cl]; nn[u] = ee < end ? csr_norm[cl] : 0.0f;
    }
    float d = dis[node];
    short8 self = *(const short8*)(h + (size_t)node * 64 + l8 * 8);
    short8 g[8];
    #pragma unroll
    for (int u = 0; u < 8; ++u)
        g[u] = *(const short8*)(h + (size_t)idx[u] * 64 + l8 * 8);
    float a[8];
    init8(a, self, d * d);
    #pragma unroll
    for (int u = 0; u < 8; ++u) fma8(a, g[u], nn[u]);
    for (int e = beg + 8; e < end; e += 8) {         // rare remainder
        int idx2[8]; float nn2[8];
        #pragma unroll
        for (int u = 0; u < 8; ++u) {
            int ee = e + u; int cl = ee < end ? ee : end - 1;
            idx2[u] = csr_src[cl]; nn2[u] = ee < end ? csr_norm[cl] : 0.0f;
        }
        short8 g2[8];
        #pragma unroll
        for (int u = 0; u < 8; ++u)
            g2[u] = *(const short8*)(h + (size_t)idx2[u] * 64 + l8 * 8);
        #pragma unroll
        for (int u = 0; u < 8; ++u) fma8(a, g2[u], nn2[u]);
    }
    int f = l8 * 8;
    float v = 0.f;
    #pragma unroll
    for (int j = 0; j < 8; ++j)
        v = fmaf(fmaxf(a[j] + bias[f + j], 0.f), Wl[f + j], v);
    #pragma unroll
    for (int m = 4; m > 0; m >>= 1) v += __shfl_xor(v, m, 64);   // reduce within 8-lane group
    if (l8 == 0) s_out[node] = v;
}

// ---------------------------------------------------------------- pool over per-node scalars
__global__ __launch_bounds__(256) void k_pool2(const float* __restrict__ s,
                                               const int* __restrict__ batch,
                                               const float* __restrict__ bl,
                                               float* __restrict__ out) {
    int g = blockIdx.x;
    int tid = threadIdx.x;
    int lo = 0, hi = N_NODES;
    while (lo < hi) { int m = (lo + hi) >> 1; if (batch[m] < g) lo = m + 1; else hi = m; }
    int lo2 = lo, hi2 = N_NODES;
    while (lo2 < hi2) { int m = (lo2 + hi2) >> 1; if (batch[m] < g + 1) lo2 = m + 1; else hi2 = m; }
    float acc = 0.0f;
    for (int n = lo + tid; n < lo2; n += 256) acc += s[n];
    __shared__ float sm[256];
    sm[tid] = acc; __syncthreads();
    for (int off = 128; off > 0; off >>= 1) {
        if (tid < off) sm[tid] += sm[tid + off];
        __syncthreads();
    }
    if (tid == 0) out[g] = sm[0] / fmaxf((float)(lo2 - lo), 1.0f) + bl[0];
}

// ---------------------------------------------------------------- launcher
extern "C" void kernel_launch(void* const* d_in, const int* in_sizes, int n_in,
                              void* d_out, int out_size, void* d_ws, size_t ws_size,
                              hipStream_t stream) {
    const float* x     = (const float*)d_in[0];
    const int*   ei    = (const int*)d_in[1];     // [0..E) = src, [E..2E) = dst
    const int*   batch = (const int*)d_in[2];
    const float* W1 = (const float*)d_in[3];
    const float* b1 = (const float*)d_in[4];
    const float* W2 = (const float*)d_in[5];
    const float* b2 = (const float*)d_in[6];
    const float* W3 = (const float*)d_in[7];
    const float* b3 = (const float*)d_in[8];
    const float* Wl = (const float*)d_in[9];
    const float* bl = (const float*)d_in[10];
    float* out = (float*)d_out;

    const int* e_src = ei;
    const int* e_dst = ei + N_EDGES;

    char* ws = (char*)d_ws;
    size_t off = 0;
    auto alloc = [&](size_t bytes) -> char* {
        char* p = ws + off;
        off = (off + bytes + 255) & ~(size_t)255;
        return p;
    };
    int*   cnt      = (int*)  alloc((size_t)N_NODES * 4);
    float* dis      = (float*)alloc((size_t)N_NODES * 4);
    int*   row_ptr  = (int*)  alloc((size_t)(N_NODES + 1) * 4);
    int*   cursor   = (int*)  alloc((size_t)N_NODES * 4);
    int*   part     = (int*)  alloc(1024 * 4);
    int*   csr_src  = (int*)  alloc((size_t)N_EDGES * 4);
    float* csr_norm = (float*)alloc((size_t)N_EDGES * 4);
    float* nscal    = (float*)alloc((size_t)N_NODES * 4);
    unsigned short* P1b = (unsigned short*)alloc((size_t)N_NODES * 128 * 2); // h1 bf16
    unsigned short* Q2b = (unsigned short*)alloc((size_t)N_NODES * 64 * 2);  // h2@W3 bf16
    unsigned short* Wp2 = (unsigned short*)alloc((size_t)128 * 128 * 2);
    unsigned short* Wp3 = (unsigned short*)alloc((size_t)128 * 64 * 2);

    const int NB_N = (N_NODES + 255) / 256;   // 391
    const int NB_E = (N_EDGES + 255) / 256;

    hipMemsetAsync(cnt, 0, (size_t)N_NODES * 4, stream);
    k_hist<<<NB_E, 256, 0, stream>>>(e_dst, cnt);
    k_scan1<<<NB_N, 256, 0, stream>>>(cnt, part);
    k_scan3<<<NB_N, 256, 0, stream>>>(cnt, part, row_ptr, cursor, dis);
    k_scatter<<<NB_E, 256, 0, stream>>>(e_src, e_dst, dis, cursor, csr_src, csr_norm);

    // layer 1 fused: agg(F=3) + GEMM 3->128 + b1 + relu -> bf16 (+12 pack blocks)
    k_node1<<<NB1 + 12, 256, 0, stream>>>(x, dis, row_ptr, csr_src, csr_norm,
                                          W1, b1, P1b, W2, W3, Wp2, Wp3);

    // layers 2+3 fused: agg(F=128) + GEMM2(+b2,relu) + GEMM3 -> Q2b bf16
    k_layer23<<<N_NODES / 32, 256, 0, stream>>>(P1b, dis, row_ptr, csr_src, csr_norm,
                                                Wp2, b2, Wp3, Q2b);

    // layer 3 aggregation + b3 + relu + dot(Wl)  (8 nodes/wave -> 3125 blocks)
    k_agg64_dot<<<N_NODES / 8 / 4, 256, 0, stream>>>(Q2b, dis, row_ptr, csr_src, csr_norm,
                                                     b3, Wl, nscal);

    // mean pool (+ bl) over per-node scalars
    k_pool2<<<N_GRAPHS, 256, 0, stream>>>(nscal, batch, bl, out);
}

// Round 12
// 217.946 us; speedup vs baseline: 4.4081x; 1.0168x over previous
//
#include <hip/hip_runtime.h>

#define N_NODES 100000
#define N_EDGES 600000
#define N_GRAPHS 512

typedef __attribute__((ext_vector_type(8))) short short8;
typedef __attribute__((ext_vector_type(4))) float floatx4;

__device__ __forceinline__ unsigned short f2bf(float f) {   // RNE f32 -> bf16
    unsigned int u = __float_as_uint(f);
    u += 0x7FFFu + ((u >> 16) & 1u);
    return (unsigned short)(u >> 16);
}
__device__ __forceinline__ float bf_lo(unsigned int u) { return __uint_as_float(u << 16); }
__device__ __forceinline__ float bf_hi(unsigned int u) { return __uint_as_float(u & 0xFFFF0000u); }

__device__ __forceinline__ void fma8(float* a, short8 v, float n) {
    union { short8 s; unsigned int u[4]; } c; c.s = v;
    #pragma unroll
    for (int j = 0; j < 4; ++j) {
        a[2 * j]     = fmaf(bf_lo(c.u[j]), n, a[2 * j]);
        a[2 * j + 1] = fmaf(bf_hi(c.u[j]), n, a[2 * j + 1]);
    }
}
__device__ __forceinline__ void init8(float* a, short8 v, float s) {
    union { short8 s; unsigned int u[4]; } c; c.s = v;
    #pragma unroll
    for (int j = 0; j < 4; ++j) {
        a[2 * j]     = bf_lo(c.u[j]) * s;
        a[2 * j + 1] = bf_hi(c.u[j]) * s;
    }
}
__device__ __forceinline__ short8 pack8(const float* a) {
    short8 r;
    #pragma unroll
    for (int j = 0; j < 8; ++j) r[j] = (short)f2bf(a[j]);
    return r;
}

// ---------------------------------------------------------------- degree hist (cnt zeroed by memset)
__global__ void k_hist(const int* __restrict__ dst, int* cnt) {
    int e = blockIdx.x * 256 + threadIdx.x;
    if (e < N_EDGES) atomicAdd(&cnt[dst[e]], 1);
}

// ---------------------------------------------------------------- scan1: block sums of cnt
__global__ void k_scan1(const int* __restrict__ cnt, int* __restrict__ part) {
    __shared__ int s[256];
    int t = threadIdx.x;
    int i = blockIdx.x * 256 + t;
    int v = (i < N_NODES) ? cnt[i] : 0;
    s[t] = v; __syncthreads();
    for (int off = 128; off > 0; off >>= 1) {
        if (t < off) s[t] += s[t + off];
        __syncthreads();
    }
    if (t == 0) part[blockIdx.x] = s[0];
}

// ---------------------------------------------------------------- scan3: computes its own base from part[]
__global__ void k_scan3(const int* __restrict__ cnt, const int* __restrict__ part,
                        int* __restrict__ row_ptr, int* __restrict__ cursor,
                        float* __restrict__ dis) {
    __shared__ int s[256];
    __shared__ int pbaseS;
    int t = threadIdx.x;
    int psum = 0;
    for (int k = t; k < blockIdx.x; k += 256) psum += part[k];
    s[t] = psum; __syncthreads();
    for (int off = 128; off > 0; off >>= 1) {
        if (t < off) s[t] += s[t + off];
        __syncthreads();
    }
    if (t == 0) pbaseS = s[0];
    __syncthreads();
    int pbase = pbaseS;
    __syncthreads();
    int i = blockIdx.x * 256 + t;
    int v = (i < N_NODES) ? cnt[i] : 0;
    s[t] = v; __syncthreads();
    for (int off = 1; off < 256; off <<= 1) {
        int u = (t >= off) ? s[t - off] : 0;
        __syncthreads();
        s[t] += u;
        __syncthreads();
    }
    int ex = s[t] - v + pbase;
    if (i < N_NODES) {
        row_ptr[i] = ex; cursor[i] = ex;
        dis[i] = 1.0f / sqrtf((float)(v + 1));   // deg includes self-loop
    }
    if (blockIdx.x == 0 && t == 0) row_ptr[N_NODES] = N_EDGES;
}

// ---------------------------------------------------------------- CSR scatter
__global__ void k_scatter(const int* __restrict__ src, const int* __restrict__ dst,
                          const float* __restrict__ dis, int* __restrict__ cursor,
                          int* __restrict__ csr_src, float* __restrict__ csr_norm) {
    int e = blockIdx.x * 256 + threadIdx.x;
    if (e >= N_EDGES) return;
    int s = src[e], d = dst[e];
    int pos = atomicAdd(&cursor[d], 1);
    csr_src[pos] = s;
    csr_norm[pos] = dis[s] * dis[d];
}

// ---------------------------------------------------------------- pack W2/W3 to B-frag order (device fn)
__device__ __forceinline__ void pack_one(const float* __restrict__ W, unsigned short* __restrict__ out,
                                         int idx, int N) {
    int lane = idx & 63;
    int ks = (idx >> 6) & 3;
    int ct = idx >> 8;
    int n = ct * 16 + (lane & 15);
    int kbase = ks * 32 + (lane >> 4) * 8;
    #pragma unroll
    for (int j = 0; j < 8; ++j)
        out[(size_t)idx * 8 + j] = f2bf(W[(size_t)(kbase + j) * N + n]);
}

// ---------------------------------------------------------------- layer 1 fused: agg(F=3) + GEMM 3->128 + b1 + relu -> bf16
// 4 nodes/wave: 16 lanes per node. Last 12 blocks instead pack W2/W3 (fused dispatch).
#define NB1 6250
__global__ __launch_bounds__(256) void k_node1(const float* __restrict__ x,
                                               const float* __restrict__ dis,
                                               const int* __restrict__ row_ptr,
                                               const int* __restrict__ csr_src,
                                               const float* __restrict__ csr_norm,
                                               const float* __restrict__ W1,
                                               const float* __restrict__ b1,
                                               unsigned short* __restrict__ out,
                                               const float* __restrict__ W2,
                                               const float* __restrict__ W3,
                                               unsigned short* __restrict__ Wp2,
                                               unsigned short* __restrict__ Wp3) {
    int tid = threadIdx.x;
    if (blockIdx.x >= NB1) {                         // weight-pack role
        int idx = (blockIdx.x - NB1) * 256 + tid;    // 12 blocks = 3072
        if (idx < 2048) pack_one(W2, Wp2, idx, 128);
        else if (idx < 3072) pack_one(W3, Wp3, idx - 2048, 64);
        return;
    }
    __shared__ float Ws[384];
    __shared__ float bs[128];
    for (int i = tid; i < 384; i += 256) Ws[i] = W1[i];
    if (tid < 128) bs[tid] = b1[tid];
    __syncthreads();
    int gw = (blockIdx.x * 256 + tid) >> 6;          // 25000 waves
    int lane = tid & 63;
    int sub = lane >> 4, l16 = lane & 15;
    int node = gw * 4 + sub;                         // 100000 = 25000*4 exact
    int beg = row_ptr[node], end = row_ptr[node + 1];
    float p0 = 0.f, p1 = 0.f, p2 = 0.f;
    for (int e = beg + l16; e < end; e += 16) {
        int s = csr_src[e];
        float n = csr_norm[e];
        p0 = fmaf(x[s * 3 + 0], n, p0);
        p1 = fmaf(x[s * 3 + 1], n, p1);
        p2 = fmaf(x[s * 3 + 2], n, p2);
    }
    #pragma unroll
    for (int m = 8; m > 0; m >>= 1) {                // butterfly within 16-lane group
        p0 += __shfl_xor(p0, m, 64);
        p1 += __shfl_xor(p1, m, 64);
        p2 += __shfl_xor(p2, m, 64);
    }
    float d = dis[node], s2 = d * d;
    float a0 = fmaf(x[node * 3 + 0], s2, p0);
    float a1 = fmaf(x[node * 3 + 1], s2, p1);
    float a2 = fmaf(x[node * 3 + 2], s2, p2);
    int f = l16 * 8;
    float v[8];
    #pragma unroll
    for (int j = 0; j < 8; ++j)
        v[j] = fmaxf(bs[f + j] + a0 * Ws[f + j] + a1 * Ws[128 + f + j] + a2 * Ws[256 + f + j], 0.f);
    *(short8*)(out + (size_t)node * 128 + f) = pack8(v);
}

// ---------------------------------------------------------------- layers 2+3 fused:
// agg(F=128 bf16): 16 lanes/node, ALL 16 gathers (both node groups) issued before any FMA.
// -> LDS -> MFMA GEMM2 (+b2, relu) -> LDS -> MFMA GEMM3 -> Q2b
// block = 32 consecutive nodes (100000 = 3125 * 32 exact). LDS rows padded to 136 ushorts.
__global__ __launch_bounds__(256) void k_layer23(const unsigned short* __restrict__ h1,
                                                 const float* __restrict__ dis,
                                                 const int* __restrict__ row_ptr,
                                                 const int* __restrict__ csr_src,
                                                 const float* __restrict__ csr_norm,
                                                 const unsigned short* __restrict__ Wp2,
                                                 const float* __restrict__ b2,
                                                 const unsigned short* __restrict__ Wp3,
                                                 unsigned short* __restrict__ Q2b) {
    __shared__ unsigned short Asb[32][136];   // aggregated h1 tile
    __shared__ unsigned short Hsb[32][136];   // h2 tile
    int tid = threadIdx.x;
    int wave = tid >> 6, lane = tid & 63;
    int quad = lane >> 4, m16 = lane & 15;
    int base = blockIdx.x * 32;

    // ---- phase 1: 8 nodes per wave in 2 groups of 4; 16 lanes/node, 8 feats/lane.
    // All 16 gathers (A+B) in flight before any FMA: one latency round for the common case.
    {
        int sub = lane >> 4, l16 = lane & 15;
        int rA = wave * 8 + sub, rB = rA + 4;
        int nodeA = base + rA, nodeB = base + rB;
        int begA = row_ptr[nodeA], endA = row_ptr[nodeA + 1];
        int begB = row_ptr[nodeB], endB = row_ptr[nodeB + 1];
        int idxA[8], idxB[8]; float nnA[8], nnB[8];
        #pragma unroll
        for (int u = 0; u < 8; ++u) {
            int ee = begA + u; int cl = ee < endA ? ee : endA - 1;
            idxA[u] = csr_src[cl]; nnA[u] = ee < endA ? csr_norm[cl] : 0.0f;
        }
        #pragma unroll
        for (int u = 0; u < 8; ++u) {
            int ee = begB + u; int cl = ee < endB ? ee : endB - 1;
            idxB[u] = csr_src[cl]; nnB[u] = ee < endB ? csr_norm[cl] : 0.0f;
        }
        float dA = dis[nodeA], dB = dis[nodeB];
        short8 selfA = *(const short8*)(h1 + (size_t)nodeA * 128 + l16 * 8);
        short8 selfB = *(const short8*)(h1 + (size_t)nodeB * 128 + l16 * 8);

        short8 gA[8], gB[8];                       // 16 gathers of 16B all in flight
        #pragma unroll
        for (int u = 0; u < 8; ++u)
            gA[u] = *(const short8*)(h1 + (size_t)idxA[u] * 128 + l16 * 8);
        #pragma unroll
        for (int u = 0; u < 8; ++u)
            gB[u] = *(const short8*)(h1 + (size_t)idxB[u] * 128 + l16 * 8);

        float aA[8], aB[8];
        init8(aA, selfA, dA * dA);
        #pragma unroll
        for (int u = 0; u < 8; ++u) fma8(aA, gA[u], nnA[u]);
        init8(aB, selfB, dB * dB);
        #pragma unroll
        for (int u = 0; u < 8; ++u) fma8(aB, gB[u], nnB[u]);

        for (int e = begA + 8; e < endA; e += 8) {       // rare remainder (P(deg>8)~15%)
            int idx[8]; float nn[8];
            #pragma unroll
            for (int u = 0; u < 8; ++u) {
                int ee = e + u; int cl = ee < endA ? ee : endA - 1;
                idx[u] = csr_src[cl]; nn[u] = ee < endA ? csr_norm[cl] : 0.0f;
            }
            short8 g[8];
            #pragma unroll
            for (int u = 0; u < 8; ++u)
                g[u] = *(const short8*)(h1 + (size_t)idx[u] * 128 + l16 * 8);
            #pragma unroll
            for (int u = 0; u < 8; ++u) fma8(aA, g[u], nn[u]);
        }
        *(short8*)(&Asb[rA][l16 * 8]) = pack8(aA);

        for (int e = begB + 8; e < endB; e += 8) {
            int idx[8]; float nn[8];
            #pragma unroll
            for (int u = 0; u < 8; ++u) {
                int ee = e + u; int cl = ee < endB ? ee : endB - 1;
                idx[u] = csr_src[cl]; nn[u] = ee < endB ? csr_norm[cl] : 0.0f;
            }
            short8 g[8];
            #pragma unroll
            for (int u = 0; u < 8; ++u)
                g[u] = *(const short8*)(h1 + (size_t)idx[u] * 128 + l16 * 8);
            #pragma unroll
            for (int u = 0; u < 8; ++u) fma8(aB, g[u], nn[u]);
        }
        *(short8*)(&Asb[rB][l16 * 8]) = pack8(aB);
    }
    __syncthreads();

    // ---- phase 2: 32x128 = Asb(32x128) @ Wp2(128x128), +b2, relu -> Hsb
    int mt = wave & 1;                 // row tile (16 rows)
    int ch = wave >> 1;                // column half (64 cols)
    {
        short8 af[4];
        #pragma unroll
        for (int ks = 0; ks < 4; ++ks)
            af[ks] = *(const short8*)(&Asb[mt * 16 + m16][ks * 32 + quad * 8]);
        floatx4 acc[4];
        #pragma unroll
        for (int ct = 0; ct < 4; ++ct) acc[ct] = (floatx4){0.f, 0.f, 0.f, 0.f};
        #pragma unroll
        for (int ct = 0; ct < 4; ++ct) {
            int gct = ch * 4 + ct;
            #pragma unroll
            for (int ks = 0; ks < 4; ++ks) {
                short8 bf = *(const short8*)(Wp2 + ((size_t)(gct * 4 + ks) * 64 + lane) * 8);
                acc[ct] = __builtin_amdgcn_mfma_f32_16x16x32_bf16(af[ks], bf, acc[ct], 0, 0, 0);
            }
        }
        #pragma unroll
        for (int ct = 0; ct < 4; ++ct) {
            int col = (ch * 4 + ct) * 16 + m16;
            float bv = b2[col];
            #pragma unroll
            for (int r = 0; r < 4; ++r) {
                int row = mt * 16 + quad * 4 + r;
                Hsb[row][col] = f2bf(fmaxf(acc[ct][r] + bv, 0.0f));
            }
        }
    }
    __syncthreads();

    // ---- phase 3: 32x64 = Hsb(32x128) @ Wp3(128x64) -> global Q2b (bf16, no bias)
    {
        int cp = wave >> 1;            // column pair (32 cols)
        short8 hf[4];
        #pragma unroll
        for (int ks = 0; ks < 4; ++ks)
            hf[ks] = *(const short8*)(&Hsb[mt * 16 + m16][ks * 32 + quad * 8]);
        floatx4 acc3[2];
        acc3[0] = (floatx4){0.f, 0.f, 0.f, 0.f};
        acc3[1] = (floatx4){0.f, 0.f, 0.f, 0.f};
        #pragma unroll
        for (int ct = 0; ct < 2; ++ct) {
            int gct = cp * 2 + ct;
            #pragma unroll
            for (int ks = 0; ks < 4; ++ks) {
                short8 bf = *(const short8*)(Wp3 + ((size_t)(gct * 4 + ks) * 64 + lane) * 8);
                acc3[ct] = __builtin_amdgcn_mfma_f32_16x16x32_bf16(hf[ks], bf, acc3[ct], 0, 0, 0);
            }
        }
        #pragma unroll
        for (int ct = 0; ct < 2; ++ct) {
            int col = (cp * 2 + ct) * 16 + m16;
            #pragma unroll
            for (int r = 0; r < 4; ++r) {
                long row = base + mt * 16 + quad * 4 + r;
                Q2b[row * 64 + col] = f2bf(acc3[ct][r]);
            }
        }
    }
}

// ---------------------------------------------------------------- aggregation F=64 bf16 + bias + relu + Wl dot
// 8 nodes/wave: 8 lanes x 8 feats (16B short8 gathers), single gather round.
__global__ __launch_bounds__(256) void k_agg64_dot(const unsigned short* __restrict__ h,
                                                   const float* __restrict__ dis,
                                                   const int* __restrict__ row_ptr,
                                                   const int* __restrict__ csr_src,
                                                   const float* __restrict__ csr_norm,
                                                   const float* __restrict__ bias,
                                                   const float* __restrict__ Wl,
                                                   float* __restrict__ s_out) {
    int gw = (blockIdx.x * 256 + threadIdx.x) >> 6;  // 12500 waves
    int lane = threadIdx.x & 63;
    int sub = lane >> 3, l8 = lane & 7;
    int node = gw * 8 + sub;                         // 100000 = 12500*8 exact
    int beg = row_ptr[node], end = row_ptr[node + 1];
    int idx[8]; float nn[8];
    #pragma unroll
    for (int u = 0; u < 8; ++u) {
        int ee = beg + u; int cl = ee < end ? ee : end - 1;
        idx[u] = csr_src[cl]; nn[u] = ee < end ? csr_norm[cl] : 0.0f;
    }
    float d = dis[node];
    short8 self = *(const short8*)(h + (size_t)node * 64 + l8 * 8);
    short8 g[8];
    #pragma unroll
    for (int u = 0; u < 8; ++u)
        g[u] = *(const short8*)(h + (size_t)idx[u] * 64 + l8 * 8);
    float a[8];
    init8(a, self, d * d);
    #pragma unroll
    for (int u = 0; u < 8; ++u) fma8(a, g[u], nn[u]);
    for (int e = beg + 8; e < end; e += 8) {         // rare remainder
        int idx2[8]; float nn2[8];
        #pragma unroll
        for (int u = 0; u < 8; ++u) {
            int ee = e + u; int cl = ee < end ? ee : end - 1;
            idx2[u] = csr_src[cl]; nn2[u] = ee < end ? csr_norm[cl] : 0.0f;
        }
        short8 g2[8];
        #pragma unroll
        for (int u = 0; u < 8; ++u)
            g2[u] = *(const short8*)(h + (size_t)idx2[u] * 64 + l8 * 8);
        #pragma unroll
        for (int u = 0; u < 8; ++u) fma8(a, g2[u], nn2[u]);
    }
    int f = l8 * 8;
    float v = 0.f;
    #pragma unroll
    for (int j = 0; j < 8; ++j)
        v = fmaf(fmaxf(a[j] + bias[f + j], 0.f), Wl[f + j], v);
    #pragma unroll
    for (int m = 4; m > 0; m >>= 1) v += __shfl_xor(v, m, 64);   // reduce within 8-lane group
    if (l8 == 0) s_out[node] = v;
}

// ---------------------------------------------------------------- pool over per-node scalars
__global__ __launch_bounds__(256) void k_pool2(const float* __restrict__ s,
                                               const int* __restrict__ batch,
                                               const float* __restrict__ bl,
                                               float* __restrict__ out) {
    int g = blockIdx.x;
    int tid = threadIdx.x;
    int lo = 0, hi = N_NODES;
    while (lo < hi) { int m = (lo + hi) >> 1; if (batch[m] < g) lo = m + 1; else hi = m; }
    int lo2 = lo, hi2 = N_NODES;
    while (lo2 < hi2) { int m = (lo2 + hi2) >> 1; if (batch[m] < g + 1) lo2 = m + 1; else hi2 = m; }
    float acc = 0.0f;
    for (int n = lo + tid; n < lo2; n += 256) acc += s[n];
    __shared__ float sm[256];
    sm[tid] = acc; __syncthreads();
    for (int off = 128; off > 0; off >>= 1) {
        if (tid < off) sm[tid] += sm[tid + off];
        __syncthreads();
    }
    if (tid == 0) out[g] = sm[0] / fmaxf((float)(lo2 - lo), 1.0f) + bl[0];
}

// ---------------------------------------------------------------- launcher
extern "C" void kernel_launch(void* const* d_in, const int* in_sizes, int n_in,
                              void* d_out, int out_size, void* d_ws, size_t ws_size,
                              hipStream_t stream) {
    const float* x     = (const float*)d_in[0];
    const int*   ei    = (const int*)d_in[1];     // [0..E) = src, [E..2E) = dst
    const int*   batch = (const int*)d_in[2];
    const float* W1 = (const float*)d_in[3];
    const float* b1 = (const float*)d_in[4];
    const float* W2 = (const float*)d_in[5];
    const float* b2 = (const float*)d_in[6];
    const float* W3 = (const float*)d_in[7];
    const float* b3 = (const float*)d_in[8];
    const float* Wl = (const float*)d_in[9];
    const float* bl = (const float*)d_in[10];
    float* out = (float*)d_out;

    const int* e_src = ei;
    const int* e_dst = ei + N_EDGES;

    char* ws = (char*)d_ws;
    size_t off = 0;
    auto alloc = [&](size_t bytes) -> char* {
        char* p = ws + off;
        off = (off + bytes + 255) & ~(size_t)255;
        return p;
    };
    int*   cnt      = (int*)  alloc((size_t)N_NODES * 4);
    float* dis      = (float*)alloc((size_t)N_NODES * 4);
    int*   row_ptr  = (int*)  alloc((size_t)(N_NODES + 1) * 4);
    int*   cursor   = (int*)  alloc((size_t)N_NODES * 4);
    int*   part     = (int*)  alloc(1024 * 4);
    int*   csr_src  = (int*)  alloc((size_t)N_EDGES * 4);
    float* csr_norm = (float*)alloc((size_t)N_EDGES * 4);
    float* nscal    = (float*)alloc((size_t)N_NODES * 4);
    unsigned short* P1b = (unsigned short*)alloc((size_t)N_NODES * 128 * 2); // h1 bf16
    unsigned short* Q2b = (unsigned short*)alloc((size_t)N_NODES * 64 * 2);  // h2@W3 bf16
    unsigned short* Wp2 = (unsigned short*)alloc((size_t)128 * 128 * 2);
    unsigned short* Wp3 = (unsigned short*)alloc((size_t)128 * 64 * 2);

    const int NB_N = (N_NODES + 255) / 256;   // 391
    const int NB_E = (N_EDGES + 255) / 256;

    hipMemsetAsync(cnt, 0, (size_t)N_NODES * 4, stream);
    k_hist<<<NB_E, 256, 0, stream>>>(e_dst, cnt);
    k_scan1<<<NB_N, 256, 0, stream>>>(cnt, part);
    k_scan3<<<NB_N, 256, 0, stream>>>(cnt, part, row_ptr, cursor, dis);
    k_scatter<<<NB_E, 256, 0, stream>>>(e_src, e_dst, dis, cursor, csr_src, csr_norm);

    // layer 1 fused: agg(F=3) + GEMM 3->128 + b1 + relu -> bf16 (+12 pack blocks)
    k_node1<<<NB1 + 12, 256, 0, stream>>>(x, dis, row_ptr, csr_src, csr_norm,
                                          W1, b1, P1b, W2, W3, Wp2, Wp3);

    // layers 2+3 fused: agg(F=128) + GEMM2(+b2,relu) + GEMM3 -> Q2b bf16
    k_layer23<<<N_NODES / 32, 256, 0, stream>>>(P1b, dis, row_ptr, csr_src, csr_norm,
                                                Wp2, b2, Wp3, Q2b);

    // layer 3 aggregation + b3 + relu + dot(Wl)  (8 nodes/wave -> 3125 blocks)
    k_agg64_dot<<<N_NODES / 8 / 4, 256, 0, stream>>>(Q2b, dis, row_ptr, csr_src, csr_norm,
                                                     b3, Wl, nscal);

    // mean pool (+ bl) over per-node scalars
    k_pool2<<<N_GRAPHS, 256, 0, stream>>>(nscal, batch, bl, out);
}